// Round 5
// baseline (19074.893 us; speedup 1.0000x reference)
//
#include <hip/hip_runtime.h>

#define TOT   3800
#define BB    8
#define TT    1000
#define AL    0.1f

constexpr int WT_FLOATS = 4475136;   // sum of padded region blocks
constexpr int NWG       = 241;       // ITI folded into FSI wg 9's padded rows

// region order: D1, D2, FSI(+ITI), GPE, STN, SNR, THAL, ALM
__constant__ int   kWgStart[9]    = {0,33,66,76,109,142,175,208,241};
__constant__ int   kRowBase[8]    = {0,520,1040,1196,1716,2236,2756,3276};
__constant__ int   kRowCnt[8]     = {520,520,156,520,520,520,520,520};
__constant__ int   kCols[8]       = {2236,2236,1200,520,520,1040,520,1040};
__constant__ int   kWtOff[8]      = {0,1180608,2361216,2553216,2827776,3102336,3651456,3926016};
__constant__ int   kWtEnd[8]      = {1180608,2361216,2553216,2827776,3102336,3651456,3926016,4475136};
__constant__ float kTonic[8]      = {0.01f,0.01f,0.01f,0.8f,0.6f,0.8f,0.01f,0.01f};
// staging segments: packed-col ranges -> global h unit index (all lens %4 == 0)
__constant__ int   kSegStart[8][3]= {{0,2756,0},{0,2756,0},{1040,2756,3796},{520,0,0},{1196,0,0},{0,1716,0},{2236,0,0},{2756,0,0}};
__constant__ int   kSegLen[8][3]  = {{1196,1040,0},{1196,1040,0},{156,1040,4},{520,0,0},{520,0,0},{520,520,0},{520,0,0},{1040,0,0}};

struct Params {
  const float *d12d1,*d22d2,*d12d2,*d22d1,*thal2alm,*thal2d1,*thal2d2,*alm2alm,
              *alm2d1,*alm2d2,*d12snr,*d22gpe,*gpe2stn,*stn2snr,*snr2thal,
              *fsi2d1,*fsi2d2,*thal2fsi,*alm2fsi,*iti2fsi,*fsi2fsi;
  const int* mask;
};

__device__ __forceinline__ float rl(float x) { return fmaxf(x, 0.0f); }

// Build packed, pre-masked, pre-signed, ALPHA-scaled W.
// Layout per region: offset = (ugg*cols + col)*4 + j, row = ugg*4 + j
__global__ void prep_wt(Params P, float* __restrict__ Wt) {
  int e = blockIdx.x * blockDim.x + threadIdx.x;
  if (e >= WT_FLOATS) return;
  int r = 0;
  while (e >= kWtEnd[r]) ++r;
  int base  = (r == 0) ? 0 : kWtEnd[r-1];
  int local = e - base;
  int j    = local & 3;
  int q    = local >> 2;
  int cols = kCols[r];
  int col  = q % cols;
  int ugg  = q / cols;
  int row  = ugg * 4 + j;
  float v = 0.0f;
  if (row < kRowCnt[r]) {
    int c = col;
    switch (r) {
      case 0: case 1: {
        const float* pd1 = (r==0) ? P.d12d1 : P.d12d2;
        const float* pd2 = (r==0) ? P.d22d1 : P.d22d2;
        const float* pf  = (r==0) ? P.fsi2d1 : P.fsi2d2;
        const float* pt  = (r==0) ? P.thal2d1 : P.thal2d2;
        const float* pa  = (r==0) ? P.alm2d1 : P.alm2d2;
        if (c < 520)       { v = -(float)P.mask[row*520+c] * rl(pd1[row*520+c]); }
        else if (c < 1040) { int cc=c-520;  v = -(float)P.mask[row*520+cc] * rl(pd2[row*520+cc]); }
        else if (c < 1196) { int cc=c-1040; v = -rl(pf[row*156+cc]); }
        else if (c < 1716) { int cc=c-1196; v =  rl(pt[row*520+cc]); }
        else               { int cc=c-1716; v = (cc<364) ? rl(pa[row*520+cc]) : 0.0f; }
        break;
      }
      case 2: {
        if (c < 156)       { v = -rl(P.fsi2fsi[row*156+c]); }
        else if (c < 676)  { int cc=c-156; v = rl(P.thal2fsi[row*520+cc]); }
        else if (c < 1196) { int cc=c-676; v = (cc<364) ? rl(P.alm2fsi[row*520+cc]) : 0.0f; }
        else               { int cc=c-1196; v = rl(P.iti2fsi[row*4+cc]); }
        break;
      }
      case 3: v = ((row<260)==(c<260)) ? -rl(P.d22gpe[row*520+c])  : 0.0f; break;
      case 4: v = ((row<260)==(c<260)) ? -rl(P.gpe2stn[row*520+c]) : 0.0f; break;
      case 5: {
        if (c < 520) { v = ((row<260)==(c<260)) ? -rl(P.d12snr[row*520+c]) : 0.0f; }
        else { int cc=c-520; v = ((row<260)==(cc<260)) ? rl(P.stn2snr[row*520+cc]) : 0.0f; }
        break;
      }
      case 6: v = ((row<260)==(c<260)) ? -rl(P.snr2thal[row*520+c]) : 0.0f; break;
      case 7: {
        if (c < 520) { v = rl(P.thal2alm[row*520+c]); }
        else { int cc=c-520; v = rl(P.alm2alm[row*520+cc]) * ((cc<364) ? 1.0f : -1.0f); }
        break;
      }
    }
    v *= AL;
  }
  Wt[e] = v;
}

// h is b-major: h[b*TOT + u] — identical layout to hn, plain copy
__global__ void init_h(const float* __restrict__ hn, float* __restrict__ h0) {
  int i = blockIdx.x * blockDim.x + threadIdx.x;
  if (i < TOT * BB) h0[i] = hn[i];
}

__global__ void zero_bar(unsigned* __restrict__ bar) {
  if (threadIdx.x < 272) bar[threadIdx.x] = 0u;
}

__device__ __forceinline__ float2 agld2(const float* p) {
  unsigned long long v = __hip_atomic_load((const unsigned long long*)p,
                                           __ATOMIC_RELAXED, __HIP_MEMORY_SCOPE_AGENT);
  float2 r;
  r.x = __uint_as_float((unsigned)(v & 0xffffffffull));
  r.y = __uint_as_float((unsigned)(v >> 32));
  return r;
}
__device__ __forceinline__ void agst(float* p, float v) {
  __hip_atomic_store(p, v, __ATOMIC_RELAXED, __HIP_MEMORY_SCOPE_AGENT);
}

#define CF(W, HX) \
  acc[0][b] = fmaf((W).x, (HX), acc[0][b]); \
  acc[1][b] = fmaf((W).y, (HX), acc[1][b]); \
  acc[2][b] = fmaf((W).z, (HX), acc[2][b]); \
  acc[3][b] = fmaf((W).w, (HX), acc[3][b]);

// 1024 threads/WG, W in registers, all-b128 LDS, custom 2-level grid barrier.
// thread = (rg = tid>>8 : 4-row group, sp = tid&255 : 4-col chunk split)
// chunks: ch0 = sp, ch1 = sp+256, tail chunk 512+(tid&63) on wave (tid>>6&3)==rg
__global__ void __launch_bounds__(1024, 4)
rnn_scan(const float* __restrict__ Wt, const float* __restrict__ noise,
         const float* __restrict__ inp, float* __restrict__ out,
         float* __restrict__ h0, float* __restrict__ h1,
         unsigned* __restrict__ bar) {
  __shared__ float4 S4[8192];   // union: h chunks [8][576] / partials Pv[32][256]
  const int bid = blockIdx.x, tid = threadIdx.x;
  int r = 0;
  while (bid >= kWgStart[r + 1]) ++r;

  unsigned* cnt1 = bar;          // 8 groups, stride 32 words (128B apart)
  unsigned* cnt0 = bar + 256;
  unsigned* flag = bar + 257;
  const int g8   = bid & 7;
  const unsigned gsz = (g8 == 0) ? 31u : 30u;

  const int wgl     = bid - kWgStart[r];
  const int cols    = kCols[r];
  const int rowcnt  = kRowCnt[r];
  const int rowbase = kRowBase[r];
  const int rg = tid >> 8, sp = tid & 255;
  const int ugg = wgl * 4 + rg;
  const float* wtp = Wt + (size_t)kWtOff[r];
  const float ton = kTonic[r];
  const int l0 = kSegLen[r][0], l1 = kSegLen[r][1];
  const int g0 = kSegStart[r][0], g1 = kSegStart[r][1], g2 = kSegStart[r][2];

  const bool hastail = (((tid >> 6) & 3) == rg);
  const int  chT     = 512 + (tid & 63);

  // ---- W fragments into registers (persist across all 1000 steps)
  float4 w0[4], w1[4], w2[4];
  #pragma unroll
  for (int q = 0; q < 4; ++q) {
    int cA = sp * 4 + q, cB = (sp + 256) * 4 + q, cC = chT * 4 + q;
    w0[q] = (cA < cols) ? *(const float4*)(wtp + ((size_t)ugg * cols + cA) * 4) : make_float4(0,0,0,0);
    w1[q] = (cB < cols) ? *(const float4*)(wtp + ((size_t)ugg * cols + cB) * 4) : make_float4(0,0,0,0);
    w2[q] = (hastail && cC < cols) ? *(const float4*)(wtp + ((size_t)ugg * cols + cC) * 4) : make_float4(0,0,0,0);
  }

  // ---- t-invariant staging tasks: task = bb*576 + ch (lanes contiguous in ch)
  // pk = ((go+1)<<13) | dsix ; go = -1 => zero-fill ; pk = -1 => no task
  int pkk[5];
  #pragma unroll
  for (int k2 = 0; k2 < 5; ++k2) {
    int task = tid + (k2 << 10);
    if (task < 4608) {
      int bb = task / 576, ch = task - bb * 576;
      int c4 = ch * 4;
      int go = -1;
      if (c4 < cols) {
        int g;
        if (c4 < l0)           g = g0 + c4;
        else if (c4 < l0 + l1) g = g1 + (c4 - l0);
        else                   g = g2 + (c4 - l0 - l1);
        go = bb * TOT + g;
      }
      pkk[k2] = ((go + 1) << 13) | (bb * 576 + ch);
    } else pkk[k2] = -1;
  }

  // ---- epilogue owner: tid&31==0 owns (row = ri>>1, b-quad bh = ri&1), ri = tid>>5
  const int  ri    = tid >> 5, kk = tid & 31;
  const int  erow  = ri >> 1, bh = ri & 1, eb0 = bh * 4;
  const int  erowl = wgl * 16 + erow;
  const bool eiti  = (r == 2) && (wgl == 9) && (kk == 0) && (erowl >= 156);
  const bool ewr   = (kk == 0) && (erowl < rowcnt);
  const int  erg   = eiti ? (3796 + (erowl - 156)) : (rowbase + erowl);
  const bool own   = ewr || eiti;
  const float tonf = eiti ? 0.0f : ton;
  const size_t SB  = (size_t)TT * TOT;

  float4 hp = {0,0,0,0}, nz = {0,0,0,0}, ii = {0,0,0,0};
  if (own) {
    hp.x = h0[(eb0+0)*TOT + erg]; hp.y = h0[(eb0+1)*TOT + erg];
    hp.z = h0[(eb0+2)*TOT + erg]; hp.w = h0[(eb0+3)*TOT + erg];
    const float* np = noise + erg;
    nz.x = np[(eb0+0)*SB]; nz.y = np[(eb0+1)*SB];
    nz.z = np[(eb0+2)*SB]; nz.w = np[(eb0+3)*SB];
    if (eiti) {
      int ik = erg - 3796;
      ii.x = inp[((size_t)(eb0+0)*TT)*4 + ik]; ii.y = inp[((size_t)(eb0+1)*TT)*4 + ik];
      ii.z = inp[((size_t)(eb0+2)*TT)*4 + ik]; ii.w = inp[((size_t)(eb0+3)*TT)*4 + ik];
    }
  }

  for (int t = 0; t < TT; ++t) {
    const float* __restrict__ hc = (t & 1) ? h1 : h0;
    float*       __restrict__ hx = (t & 1) ? h0 : h1;

    // ---- stage h chunks: S4[bb*576 + ch] = h[bb][4ch..4ch+3]  (2x b64 agent loads)
    #pragma unroll
    for (int k2 = 0; k2 < 5; ++k2) {
      int pk = pkk[k2];
      if (pk >= 0) {
        int ds = pk & 8191;
        int go = (pk >> 13) - 1;
        float4 v = make_float4(0.f, 0.f, 0.f, 0.f);
        if (go >= 0) {
          float2 a  = agld2(hc + go);
          float2 b2 = agld2(hc + go + 2);
          v = make_float4(a.x, a.y, b2.x, b2.y);
        }
        S4[ds] = v;
      }
    }
    __syncthreads();

    // ---- FMA: contiguous ds_read_b128, 16 FMA per (chunk,b)
    float acc[4][8];
    #pragma unroll
    for (int r2 = 0; r2 < 4; ++r2)
      #pragma unroll
      for (int b = 0; b < 8; ++b) acc[r2][b] = 0.f;

    #pragma unroll
    for (int b = 0; b < 8; ++b) {
      float4 hv = S4[b * 576 + sp];
      CF(w0[0], hv.x) CF(w0[1], hv.y) CF(w0[2], hv.z) CF(w0[3], hv.w)
    }
    #pragma unroll
    for (int b = 0; b < 8; ++b) {
      float4 hv = S4[b * 576 + 256 + sp];
      CF(w1[0], hv.x) CF(w1[1], hv.y) CF(w1[2], hv.z) CF(w1[3], hv.w)
    }
    if (hastail) {
      #pragma unroll
      for (int b = 0; b < 8; ++b) {
        float4 hv = S4[b * 576 + chT];
        CF(w2[0], hv.x) CF(w2[1], hv.y) CF(w2[2], hv.z) CF(w2[3], hv.w)
      }
    }
    __syncthreads();   // done reading h; reuse S4 as Pv

    // ---- partials: Pv[(rg*4+r2)*2+bh2][sp] (contiguous b128 writes)
    #pragma unroll
    for (int r2 = 0; r2 < 4; ++r2) {
      S4[(((rg * 4 + r2) << 1) | 0) * 256 + sp] = make_float4(acc[r2][0], acc[r2][1], acc[r2][2], acc[r2][3]);
      S4[(((rg * 4 + r2) << 1) | 1) * 256 + sp] = make_float4(acc[r2][4], acc[r2][5], acc[r2][6], acc[r2][7]);
    }
    __syncthreads();

    // ---- reduce: group ri (32 lanes) sums 256 sp slots, then 5-level shfl
    float4 sv = {0,0,0,0};
    #pragma unroll
    for (int it = 0; it < 8; ++it) {
      float4 p = S4[ri * 256 + kk + (it << 5)];
      sv.x += p.x; sv.y += p.y; sv.z += p.z; sv.w += p.w;
    }
    #pragma unroll
    for (int m = 1; m <= 16; m <<= 1) {
      sv.x += __shfl_xor(sv.x, m);
      sv.y += __shfl_xor(sv.y, m);
      sv.z += __shfl_xor(sv.z, m);
      sv.w += __shfl_xor(sv.w, m);
    }

    float4 x = {0,0,0,0};
    if (own) {
      x.x = fmaxf(fmaf(0.9f, hp.x, sv.x + AL * (tonf + nz.x + ii.x)), 0.0f);
      x.y = fmaxf(fmaf(0.9f, hp.y, sv.y + AL * (tonf + nz.y + ii.y)), 0.0f);
      x.z = fmaxf(fmaf(0.9f, hp.z, sv.z + AL * (tonf + nz.z + ii.z)), 0.0f);
      x.w = fmaxf(fmaf(0.9f, hp.w, sv.w + AL * (tonf + nz.w + ii.w)), 0.0f);
      agst(&hx[(eb0+0)*TOT + erg], x.x);
      agst(&hx[(eb0+1)*TOT + erg], x.y);
      agst(&hx[(eb0+2)*TOT + erg], x.z);
      agst(&hx[(eb0+3)*TOT + erg], x.w);
    }
    __syncthreads();   // drain hx stores (vmcnt(0) before s_barrier)

    // ---- arrive (release: all WG stores LLC-acked before the count)
    if (tid == 0) {
      unsigned old = atomicAdd(&cnt1[g8 * 32], 1u);
      if (old + 1 == gsz * (unsigned)(t + 1)) {
        unsigned o0 = atomicAdd(cnt0, 1u);
        if (o0 + 1 == 8u * (unsigned)(t + 1)) {
          __hip_atomic_store(flag, (unsigned)(t + 1), __ATOMIC_RELAXED, __HIP_MEMORY_SCOPE_AGENT);
        }
      }
    }

    // ---- independent work hidden under the barrier: out-store + t+1 prefetch
    if (own) {
      float* op = out + (size_t)eb0 * SB + (size_t)t * TOT + erg;
      op[0] = x.x; op[SB] = x.y; op[2*SB] = x.z; op[3*SB] = x.w;
      hp = x;
      if (t + 1 < TT) {
        const float* np = noise + erg + (size_t)(t + 1) * TOT;
        nz.x = np[(eb0+0)*SB]; nz.y = np[(eb0+1)*SB];
        nz.z = np[(eb0+2)*SB]; nz.w = np[(eb0+3)*SB];
        if (eiti) {
          int ik = erg - 3796;
          const float* ip = inp + (size_t)(t + 1) * 4 + ik;
          ii.x = ip[(size_t)(eb0+0)*TT*4]; ii.y = ip[(size_t)(eb0+1)*TT*4];
          ii.z = ip[(size_t)(eb0+2)*TT*4]; ii.w = ip[(size_t)(eb0+3)*TT*4];
        }
      }
    }

    // ---- wait
    if (tid == 0) {
      while (__hip_atomic_load(flag, __ATOMIC_RELAXED, __HIP_MEMORY_SCOPE_AGENT) < (unsigned)(t + 1)) {}
    }
    __syncthreads();
  }
}

extern "C" void kernel_launch(void* const* d_in, const int* in_sizes, int n_in,
                              void* d_out, int out_size, void* d_ws, size_t ws_size,
                              hipStream_t stream) {
  Params P;
  P.d12d1   = (const float*)d_in[0];  P.d22d2   = (const float*)d_in[1];
  P.d12d2   = (const float*)d_in[2];  P.d22d1   = (const float*)d_in[3];
  P.thal2alm= (const float*)d_in[4];  P.thal2d1 = (const float*)d_in[5];
  P.thal2d2 = (const float*)d_in[6];  P.alm2alm = (const float*)d_in[7];
  P.alm2d1  = (const float*)d_in[8];  P.alm2d2  = (const float*)d_in[9];
  P.d12snr  = (const float*)d_in[10]; P.d22gpe  = (const float*)d_in[11];
  P.gpe2stn = (const float*)d_in[12]; P.stn2snr = (const float*)d_in[13];
  P.snr2thal= (const float*)d_in[14]; P.fsi2d1  = (const float*)d_in[15];
  P.fsi2d2  = (const float*)d_in[16]; P.thal2fsi= (const float*)d_in[17];
  P.alm2fsi = (const float*)d_in[18]; P.iti2fsi = (const float*)d_in[19];
  P.fsi2fsi = (const float*)d_in[20]; P.mask    = (const int*)d_in[21];
  const float* inp   = (const float*)d_in[22];
  const float* hn    = (const float*)d_in[23];
  const float* noise = (const float*)d_in[24];

  float* ws = (float*)d_ws;
  float* Wt = ws;
  float* h0 = ws + WT_FLOATS;
  float* h1 = h0 + TOT * BB;
  unsigned* bar = (unsigned*)(h1 + TOT * BB);

  hipLaunchKernelGGL(prep_wt,  dim3((WT_FLOATS + 255) / 256), dim3(256), 0, stream, P, Wt);
  hipLaunchKernelGGL(init_h,   dim3((TOT * BB + 255) / 256),  dim3(256), 0, stream, hn, h0);
  hipLaunchKernelGGL(zero_bar, dim3(1), dim3(512), 0, stream, bar);

  const float* WtA = Wt; const float* noiseA = noise; const float* inpA = inp;
  float* outA = (float*)d_out; float* h0A = h0; float* h1A = h1; unsigned* barA = bar;
  void* kargs[7] = {&WtA, &noiseA, &inpA, &outA, &h0A, &h1A, &barA};
  hipLaunchCooperativeKernel((const void*)rnn_scan, dim3(NWG), dim3(1024), kargs, 0, stream);
}

// Round 6
// 14964.169 us; speedup vs baseline: 1.2747x; 1.2747x over previous
//
#include <hip/hip_runtime.h>

#define TOT   3800
#define BB    8
#define TT    1000
#define AL    0.1f

constexpr int WT_FLOATS = 4475136;   // sum of padded region blocks
constexpr int NWG       = 241;       // ITI folded into FSI wg 9's padded rows

// region order: D1, D2, FSI(+ITI), GPE, STN, SNR, THAL, ALM
__constant__ int   kWgStart[9]    = {0,33,66,76,109,142,175,208,241};
__constant__ int   kRowBase[8]    = {0,520,1040,1196,1716,2236,2756,3276};
__constant__ int   kRowCnt[8]     = {520,520,156,520,520,520,520,520};
__constant__ int   kCols[8]       = {2236,2236,1200,520,520,1040,520,1040};
__constant__ int   kWtOff[8]      = {0,1180608,2361216,2553216,2827776,3102336,3651456,3926016};
__constant__ int   kWtEnd[8]      = {1180608,2361216,2553216,2827776,3102336,3651456,3926016,4475136};
__constant__ float kTonic[8]      = {0.01f,0.01f,0.01f,0.8f,0.6f,0.8f,0.01f,0.01f};
// staging segments: packed-col ranges -> global h unit index (all lens %4 == 0)
__constant__ int   kSegStart[8][3]= {{0,2756,0},{0,2756,0},{1040,2756,3796},{520,0,0},{1196,0,0},{0,1716,0},{2236,0,0},{2756,0,0}};
__constant__ int   kSegLen[8][3]  = {{1196,1040,0},{1196,1040,0},{156,1040,4},{520,0,0},{520,0,0},{520,520,0},{520,0,0},{1040,0,0}};

struct Params {
  const float *d12d1,*d22d2,*d12d2,*d22d1,*thal2alm,*thal2d1,*thal2d2,*alm2alm,
              *alm2d1,*alm2d2,*d12snr,*d22gpe,*gpe2stn,*stn2snr,*snr2thal,
              *fsi2d1,*fsi2d2,*thal2fsi,*alm2fsi,*iti2fsi,*fsi2fsi;
  const int* mask;
};

__device__ __forceinline__ float rl(float x) { return fmaxf(x, 0.0f); }

// Build packed, pre-masked, pre-signed, ALPHA-scaled W.
// Layout per region: offset = (ugg*cols + col)*4 + j, row = ugg*4 + j
__global__ void prep_wt(Params P, float* __restrict__ Wt) {
  int e = blockIdx.x * blockDim.x + threadIdx.x;
  if (e >= WT_FLOATS) return;
  int r = 0;
  while (e >= kWtEnd[r]) ++r;
  int base  = (r == 0) ? 0 : kWtEnd[r-1];
  int local = e - base;
  int j    = local & 3;
  int q    = local >> 2;
  int cols = kCols[r];
  int col  = q % cols;
  int ugg  = q / cols;
  int row  = ugg * 4 + j;
  float v = 0.0f;
  if (row < kRowCnt[r]) {
    int c = col;
    switch (r) {
      case 0: case 1: {
        const float* pd1 = (r==0) ? P.d12d1 : P.d12d2;
        const float* pd2 = (r==0) ? P.d22d1 : P.d22d2;
        const float* pf  = (r==0) ? P.fsi2d1 : P.fsi2d2;
        const float* pt  = (r==0) ? P.thal2d1 : P.thal2d2;
        const float* pa  = (r==0) ? P.alm2d1 : P.alm2d2;
        if (c < 520)       { v = -(float)P.mask[row*520+c] * rl(pd1[row*520+c]); }
        else if (c < 1040) { int cc=c-520;  v = -(float)P.mask[row*520+cc] * rl(pd2[row*520+cc]); }
        else if (c < 1196) { int cc=c-1040; v = -rl(pf[row*156+cc]); }
        else if (c < 1716) { int cc=c-1196; v =  rl(pt[row*520+cc]); }
        else               { int cc=c-1716; v = (cc<364) ? rl(pa[row*520+cc]) : 0.0f; }
        break;
      }
      case 2: {
        if (c < 156)       { v = -rl(P.fsi2fsi[row*156+c]); }
        else if (c < 676)  { int cc=c-156; v = rl(P.thal2fsi[row*520+cc]); }
        else if (c < 1196) { int cc=c-676; v = (cc<364) ? rl(P.alm2fsi[row*520+cc]) : 0.0f; }
        else               { int cc=c-1196; v = rl(P.iti2fsi[row*4+cc]); }
        break;
      }
      case 3: v = ((row<260)==(c<260)) ? -rl(P.d22gpe[row*520+c])  : 0.0f; break;
      case 4: v = ((row<260)==(c<260)) ? -rl(P.gpe2stn[row*520+c]) : 0.0f; break;
      case 5: {
        if (c < 520) { v = ((row<260)==(c<260)) ? -rl(P.d12snr[row*520+c]) : 0.0f; }
        else { int cc=c-520; v = ((row<260)==(cc<260)) ? rl(P.stn2snr[row*520+cc]) : 0.0f; }
        break;
      }
      case 6: v = ((row<260)==(c<260)) ? -rl(P.snr2thal[row*520+c]) : 0.0f; break;
      case 7: {
        if (c < 520) { v = rl(P.thal2alm[row*520+c]); }
        else { int cc=c-520; v = rl(P.alm2alm[row*520+cc]) * ((cc<364) ? 1.0f : -1.0f); }
        break;
      }
    }
    v *= AL;
  }
  Wt[e] = v;
}

// h is b-major: h[b*TOT + u] — identical layout to hn, plain copy
__global__ void init_h(const float* __restrict__ hn, float* __restrict__ h0) {
  int i = blockIdx.x * blockDim.x + threadIdx.x;
  if (i < TOT * BB) h0[i] = hn[i];
}

__global__ void zero_bar(unsigned* __restrict__ bar) {
  if (threadIdx.x < 272) bar[threadIdx.x] = 0u;
}

__device__ __forceinline__ float2 agld2(const float* p) {
  unsigned long long v = __hip_atomic_load((const unsigned long long*)p,
                                           __ATOMIC_RELAXED, __HIP_MEMORY_SCOPE_AGENT);
  float2 r;
  r.x = __uint_as_float((unsigned)(v & 0xffffffffull));
  r.y = __uint_as_float((unsigned)(v >> 32));
  return r;
}
__device__ __forceinline__ void agst(float* p, float v) {
  __hip_atomic_store(p, v, __ATOMIC_RELAXED, __HIP_MEMORY_SCOPE_AGENT);
}

// acc[qq][row j in quad][batch b] += W(rows of quad, col) * h(col, b)
#define CF2(QQ, W, HX) \
  acc[QQ][0][b] = fmaf((W).x, (HX), acc[QQ][0][b]); \
  acc[QQ][1][b] = fmaf((W).y, (HX), acc[QQ][1][b]); \
  acc[QQ][2][b] = fmaf((W).z, (HX), acc[QQ][2][b]); \
  acc[QQ][3][b] = fmaf((W).w, (HX), acc[QQ][3][b]);

// 512 threads/WG (8 waves, 1 WG/CU, 2 waves/SIMD -> 256 VGPR/thread budget).
// Thread = (rg = tid>>8 : quad-pair, sp = tid&255 : 4-col chunk split).
// Each thread owns 8 rows (quads wgl*4+rg*2+{0,1}) x chunks {sp, sp+256, tail}.
// All LDS traffic is contiguous b128. W (96 VGPR) + acc (64) live in registers.
__global__ void __launch_bounds__(512, 2)
rnn_scan(const float* __restrict__ Wt, const float* __restrict__ noise,
         const float* __restrict__ inp, float* __restrict__ out,
         float* __restrict__ h0, float* __restrict__ h1,
         unsigned* __restrict__ bar) {
  __shared__ float4 S4[8192];   // union: h chunks [8][576] (4608) / partials [32][256]
  const int bid = blockIdx.x, tid = threadIdx.x;
  int r = 0;
  while (bid >= kWgStart[r + 1]) ++r;

  unsigned* cnt1 = bar;          // 8 groups, stride 32 words (128B apart)
  unsigned* cnt0 = bar + 256;
  unsigned* flag = bar + 257;
  const int g8   = bid & 7;
  const unsigned gsz = (g8 == 0) ? 31u : 30u;

  const int wgl     = bid - kWgStart[r];
  const int cols    = kCols[r];
  const int rowcnt  = kRowCnt[r];
  const int rowbase = kRowBase[r];
  const int rg = tid >> 8, sp = tid & 255;
  const float* wtp = Wt + (size_t)kWtOff[r];
  const float ton = kTonic[r];
  const int l0 = kSegLen[r][0], l1 = kSegLen[r][1];
  const int g0 = kSegStart[r][0], g1 = kSegStart[r][1], g2 = kSegStart[r][2];

  // tail chunks 512..575: rg0 -> wave 0 (SIMD0), rg1 -> wave 7 (SIMD3)
  const bool hastail = (rg == 0) ? (sp < 64) : (sp >= 192);
  const int  chT     = 512 + (sp & 63);

  // ---- W fragments into registers: w[qq][0..3]=chunk sp, [4..7]=sp+256, [8..11]=tail
  float4 w[2][12];
  #pragma unroll
  for (int qq = 0; qq < 2; ++qq) {
    const int ug = wgl * 4 + rg * 2 + qq;
    const float* wb = wtp + (size_t)ug * cols * 4;
    #pragma unroll
    for (int q = 0; q < 4; ++q) {
      int cA = sp * 4 + q, cB = (sp + 256) * 4 + q, cC = chT * 4 + q;
      w[qq][q]     = (cA < cols) ? *(const float4*)(wb + (size_t)cA * 4) : make_float4(0,0,0,0);
      w[qq][4 + q] = (cB < cols) ? *(const float4*)(wb + (size_t)cB * 4) : make_float4(0,0,0,0);
      w[qq][8 + q] = (hastail && cC < cols) ? *(const float4*)(wb + (size_t)cC * 4) : make_float4(0,0,0,0);
    }
  }

  // ---- t-invariant staging offsets: task = tid + k*512 = bb*576 + ch (9 exact)
  int goff[9];
  #pragma unroll
  for (int k2 = 0; k2 < 9; ++k2) {
    int task = tid + (k2 << 9);
    int bb = task / 576, ch = task - bb * 576;
    int c4 = ch * 4;
    int go = -1;
    if (c4 < cols) {
      int g;
      if (c4 < l0)           g = g0 + c4;
      else if (c4 < l0 + l1) g = g1 + (c4 - l0);
      else                   g = g2 + (c4 - l0 - l1);
      go = bb * TOT + g;
    }
    goff[k2] = go;
  }

  // ---- reduce/epilogue roles: group ri = tid>>4 in [0,32) = (row16 = ri>>1, bh = ri&1)
  const int  ri    = tid >> 4, kk = tid & 15;
  const int  lo    = (kk + ri) & 15;          // bank-phase rotation
  const int  erow  = ri >> 1, bh = ri & 1, eb0 = bh * 4;
  const int  erowl = wgl * 16 + erow;
  const bool eiti  = (r == 2) && (wgl == 9) && (kk == 0) && (erowl >= 156);
  const bool ewr   = (kk == 0) && (erowl < rowcnt);
  const int  erg   = eiti ? (3796 + (erowl - 156)) : (rowbase + erowl);
  const bool own   = ewr || eiti;
  const float tonf = eiti ? 0.0f : ton;
  const size_t SB  = (size_t)TT * TOT;

  float4 hp = {0,0,0,0}, nz = {0,0,0,0}, ii = {0,0,0,0};
  if (own) {
    hp.x = h0[(eb0+0)*TOT + erg]; hp.y = h0[(eb0+1)*TOT + erg];
    hp.z = h0[(eb0+2)*TOT + erg]; hp.w = h0[(eb0+3)*TOT + erg];
    const float* np = noise + erg;
    nz.x = np[(eb0+0)*SB]; nz.y = np[(eb0+1)*SB];
    nz.z = np[(eb0+2)*SB]; nz.w = np[(eb0+3)*SB];
    if (eiti) {
      int ik = erg - 3796;
      ii.x = inp[((size_t)(eb0+0)*TT)*4 + ik]; ii.y = inp[((size_t)(eb0+1)*TT)*4 + ik];
      ii.z = inp[((size_t)(eb0+2)*TT)*4 + ik]; ii.w = inp[((size_t)(eb0+3)*TT)*4 + ik];
    }
  }

  for (int t = 0; t < TT; ++t) {
    const float* __restrict__ hc = (t & 1) ? h1 : h0;
    float*       __restrict__ hx = (t & 1) ? h0 : h1;

    // ---- stage h chunks: S4[bb*576 + ch] = h[bb][4ch..4ch+3]  (2x b64 agent loads)
    #pragma unroll
    for (int k2 = 0; k2 < 9; ++k2) {
      int go = goff[k2];
      float4 v = make_float4(0.f, 0.f, 0.f, 0.f);
      if (go >= 0) {
        float2 a  = agld2(hc + go);
        float2 b2 = agld2(hc + go + 2);
        v = make_float4(a.x, a.y, b2.x, b2.y);
      }
      S4[tid + (k2 << 9)] = v;
    }
    __syncthreads();

    // ---- FMA: contiguous ds_read_b128; each read feeds 32 FMAs (8 rows)
    float acc[2][4][8];
    #pragma unroll
    for (int qq = 0; qq < 2; ++qq)
      #pragma unroll
      for (int j2 = 0; j2 < 4; ++j2)
        #pragma unroll
        for (int b = 0; b < 8; ++b) acc[qq][j2][b] = 0.f;

    #pragma unroll
    for (int b = 0; b < 8; ++b) {
      float4 hv = S4[b * 576 + sp];
      CF2(0, w[0][0], hv.x) CF2(0, w[0][1], hv.y) CF2(0, w[0][2], hv.z) CF2(0, w[0][3], hv.w)
      CF2(1, w[1][0], hv.x) CF2(1, w[1][1], hv.y) CF2(1, w[1][2], hv.z) CF2(1, w[1][3], hv.w)
    }
    #pragma unroll
    for (int b = 0; b < 8; ++b) {
      float4 hv = S4[b * 576 + 256 + sp];
      CF2(0, w[0][4], hv.x) CF2(0, w[0][5], hv.y) CF2(0, w[0][6], hv.z) CF2(0, w[0][7], hv.w)
      CF2(1, w[1][4], hv.x) CF2(1, w[1][5], hv.y) CF2(1, w[1][6], hv.z) CF2(1, w[1][7], hv.w)
    }
    if (hastail) {
      #pragma unroll
      for (int b = 0; b < 8; ++b) {
        float4 hv = S4[b * 576 + chT];
        CF2(0, w[0][8], hv.x) CF2(0, w[0][9], hv.y) CF2(0, w[0][10], hv.z) CF2(0, w[0][11], hv.w)
        CF2(1, w[1][8], hv.x) CF2(1, w[1][9], hv.y) CF2(1, w[1][10], hv.z) CF2(1, w[1][11], hv.w)
      }
    }
    __syncthreads();   // done reading h; reuse S4 as partials

    // ---- partials: S4[(row16*2+bh)*256 + sp], contiguous b128 writes
    #pragma unroll
    for (int qq = 0; qq < 2; ++qq)
      #pragma unroll
      for (int j2 = 0; j2 < 4; ++j2) {
        int row16 = (rg * 2 + qq) * 4 + j2;
        S4[((row16 << 1) | 0) * 256 + sp] = make_float4(acc[qq][j2][0], acc[qq][j2][1], acc[qq][j2][2], acc[qq][j2][3]);
        S4[((row16 << 1) | 1) * 256 + sp] = make_float4(acc[qq][j2][4], acc[qq][j2][5], acc[qq][j2][6], acc[qq][j2][7]);
      }
    __syncthreads();

    // ---- reduce: group ri (16 lanes) sums 256 slots (rotated start: 2-way banks max)
    float4 sv = {0,0,0,0};
    #pragma unroll
    for (int it = 0; it < 16; ++it) {
      float4 p = S4[ri * 256 + lo + (it << 4)];
      sv.x += p.x; sv.y += p.y; sv.z += p.z; sv.w += p.w;
    }
    #pragma unroll
    for (int m = 1; m <= 8; m <<= 1) {
      sv.x += __shfl_xor(sv.x, m);
      sv.y += __shfl_xor(sv.y, m);
      sv.z += __shfl_xor(sv.z, m);
      sv.w += __shfl_xor(sv.w, m);
    }

    float4 x = {0,0,0,0};
    if (own) {
      x.x = fmaxf(fmaf(0.9f, hp.x, sv.x + AL * (tonf + nz.x + ii.x)), 0.0f);
      x.y = fmaxf(fmaf(0.9f, hp.y, sv.y + AL * (tonf + nz.y + ii.y)), 0.0f);
      x.z = fmaxf(fmaf(0.9f, hp.z, sv.z + AL * (tonf + nz.z + ii.z)), 0.0f);
      x.w = fmaxf(fmaf(0.9f, hp.w, sv.w + AL * (tonf + nz.w + ii.w)), 0.0f);
      agst(&hx[(eb0+0)*TOT + erg], x.x);
      agst(&hx[(eb0+1)*TOT + erg], x.y);
      agst(&hx[(eb0+2)*TOT + erg], x.z);
      agst(&hx[(eb0+3)*TOT + erg], x.w);
    }
    __syncthreads();   // drain hx stores (vmcnt(0) before s_barrier)

    // ---- arrive (release: all WG stores LLC-acked before the count)
    if (tid == 0) {
      unsigned old = atomicAdd(&cnt1[g8 * 32], 1u);
      if (old + 1 == gsz * (unsigned)(t + 1)) {
        unsigned o0 = atomicAdd(cnt0, 1u);
        if (o0 + 1 == 8u * (unsigned)(t + 1)) {
          __hip_atomic_store(flag, (unsigned)(t + 1), __ATOMIC_RELAXED, __HIP_MEMORY_SCOPE_AGENT);
        }
      }
    }

    // ---- independent work hidden under the barrier: out-store + t+1 prefetch
    if (own) {
      float* op = out + (size_t)eb0 * SB + (size_t)t * TOT + erg;
      op[0] = x.x; op[SB] = x.y; op[2*SB] = x.z; op[3*SB] = x.w;
      hp = x;
      if (t + 1 < TT) {
        const float* np = noise + erg + (size_t)(t + 1) * TOT;
        nz.x = np[(eb0+0)*SB]; nz.y = np[(eb0+1)*SB];
        nz.z = np[(eb0+2)*SB]; nz.w = np[(eb0+3)*SB];
        if (eiti) {
          int ik = erg - 3796;
          const float* ip = inp + (size_t)(t + 1) * 4 + ik;
          ii.x = ip[(size_t)(eb0+0)*TT*4]; ii.y = ip[(size_t)(eb0+1)*TT*4];
          ii.z = ip[(size_t)(eb0+2)*TT*4]; ii.w = ip[(size_t)(eb0+3)*TT*4];
        }
      }
    }

    // ---- wait
    if (tid == 0) {
      while (__hip_atomic_load(flag, __ATOMIC_RELAXED, __HIP_MEMORY_SCOPE_AGENT) < (unsigned)(t + 1)) {}
    }
    __syncthreads();
  }
}

extern "C" void kernel_launch(void* const* d_in, const int* in_sizes, int n_in,
                              void* d_out, int out_size, void* d_ws, size_t ws_size,
                              hipStream_t stream) {
  Params P;
  P.d12d1   = (const float*)d_in[0];  P.d22d2   = (const float*)d_in[1];
  P.d12d2   = (const float*)d_in[2];  P.d22d1   = (const float*)d_in[3];
  P.thal2alm= (const float*)d_in[4];  P.thal2d1 = (const float*)d_in[5];
  P.thal2d2 = (const float*)d_in[6];  P.alm2alm = (const float*)d_in[7];
  P.alm2d1  = (const float*)d_in[8];  P.alm2d2  = (const float*)d_in[9];
  P.d12snr  = (const float*)d_in[10]; P.d22gpe  = (const float*)d_in[11];
  P.gpe2stn = (const float*)d_in[12]; P.stn2snr = (const float*)d_in[13];
  P.snr2thal= (const float*)d_in[14]; P.fsi2d1  = (const float*)d_in[15];
  P.fsi2d2  = (const float*)d_in[16]; P.thal2fsi= (const float*)d_in[17];
  P.alm2fsi = (const float*)d_in[18]; P.iti2fsi = (const float*)d_in[19];
  P.fsi2fsi = (const float*)d_in[20]; P.mask    = (const int*)d_in[21];
  const float* inp   = (const float*)d_in[22];
  const float* hn    = (const float*)d_in[23];
  const float* noise = (const float*)d_in[24];

  float* ws = (float*)d_ws;
  float* Wt = ws;
  float* h0 = ws + WT_FLOATS;
  float* h1 = h0 + TOT * BB;
  unsigned* bar = (unsigned*)(h1 + TOT * BB);

  hipLaunchKernelGGL(prep_wt,  dim3((WT_FLOATS + 255) / 256), dim3(256), 0, stream, P, Wt);
  hipLaunchKernelGGL(init_h,   dim3((TOT * BB + 255) / 256),  dim3(256), 0, stream, hn, h0);
  hipLaunchKernelGGL(zero_bar, dim3(1), dim3(512), 0, stream, bar);

  const float* WtA = Wt; const float* noiseA = noise; const float* inpA = inp;
  float* outA = (float*)d_out; float* h0A = h0; float* h1A = h1; unsigned* barA = bar;
  void* kargs[7] = {&WtA, &noiseA, &inpA, &outA, &h0A, &h1A, &barA};
  hipLaunchCooperativeKernel((const void*)rnn_scan, dim3(NWG), dim3(512), kargs, 0, stream);
}